// Round 7
// baseline (561.050 us; speedup 1.0000x reference)
//
#include <hip/hip_runtime.h>
#include <hip/hip_bf16.h>
#include <math.h>

// ---------------------------------------------------------------------------
// HomoGAT on MI355X.
//  - GEMMs: split-precision bf16 MFMA (A=Ah+Al, B=Bh+Bl, 3 products, fp32 acc)
//    with fused fast-tanh (layer 0) or fused el/er attention logits.
//  - Edge weights precomputed in a flat edge-parallel kernel (el table is
//    L2-resident) -> agg loop has a single dependency level: idx -> feat.
//  - Aggregation: CSR by dst, wave-per-node, 8 feat rows in flight, all
//    scalar traffic sequential.
// (Resubmission: previous bench hit GPUAcquisitionTimeout.)
// ---------------------------------------------------------------------------

typedef __attribute__((ext_vector_type(8))) short bf16x8;
typedef __attribute__((ext_vector_type(4))) float f32x4;

__device__ __forceinline__ void split2(float v, short& h, short& l) {
    __hip_bfloat16 bh = __float2bfloat16(v);
    float r = v - __bfloat162float(bh);
    __hip_bfloat16 bl = __float2bfloat16(r);
    h = *reinterpret_cast<short*>(&bh);
    l = *reinterpret_cast<short*>(&bl);
}

__device__ __forceinline__ float fast_tanh(float x) {
    x = fminf(fmaxf(x, -15.f), 15.f);
    float e = __expf(2.f * x);
    return (e - 1.f) * __builtin_amdgcn_rcpf(e + 1.f);
}

__device__ __forceinline__ float leaky02(float x) { return x > 0.f ? x : 0.2f * x; }

__device__ __forceinline__ float sel_head(float4 q, int h) {
    float lo = (h & 1) ? q.y : q.x;
    float hi = (h & 1) ? q.w : q.z;
    return (h & 2) ? hi : lo;
}

// ---------------- weight split (all 3 weight matrices in one launch) -------
__global__ __launch_bounds__(256) void wsplit3_kernel(
        const float* __restrict__ W0, short* __restrict__ B0h, short* __restrict__ B0l,
        const float* __restrict__ W1, short* __restrict__ B1h, short* __restrict__ B1l,
        const float* __restrict__ W2, short* __restrict__ B2h, short* __restrict__ B2l) {
    int idx = blockIdx.x * 256 + threadIdx.x;
    const float* W;
    short *Bh, *Bl;
    int K, rel;
    if (idx < 128 * 256) {
        W = W0; Bh = B0h; Bl = B0l; K = 128; rel = idx;
    } else if (idx < 128 * 256 + 256 * 256) {
        W = W1; Bh = B1h; Bl = B1l; K = 256; rel = idx - 128 * 256;
    } else if (idx < 128 * 256 + 2 * 256 * 256) {
        W = W2; Bh = B2h; Bl = B2l; K = 256; rel = idx - 128 * 256 - 256 * 256;
    } else {
        return;
    }
    int k = rel >> 8, n = rel & 255;
    short h, l;
    split2(W[rel], h, l);
    Bh[n * K + k] = h;
    Bl[n * K + k] = l;
}

// ---------------- MFMA GEMM: C[M,256] = A[M,K] @ B[K,256] ------------------
template<bool TANH, bool ELER>
__global__ __launch_bounds__(256, 2) void mfma_gemm_kernel(
        const float* __restrict__ A, const short* __restrict__ Bh,
        const short* __restrict__ Bl, float* __restrict__ C, int M, int K,
        const float* __restrict__ al, const float* __restrict__ ar,
        float* __restrict__ el, float* __restrict__ er) {
    __shared__ __align__(16) short As_h[128 * 32];
    __shared__ __align__(16) short As_l[128 * 32];
    __shared__ __align__(16) short Bs_h[128 * 32];
    __shared__ __align__(16) short Bs_l[128 * 32];

    const int tid = threadIdx.x;
    const int row0 = blockIdx.x * 128;
    const int col0 = blockIdx.y * 128;

    const int sr = tid >> 1;          // 0..127
    const int sc = (tid & 1) << 4;    // 0 or 16

    const int lane = tid & 63;
    const int lr = lane & 15;
    const int lg = lane >> 4;
    const int wid = tid >> 6;
    const int wm = wid >> 1;
    const int wn = wid & 1;

    f32x4 acc[4][4];
#pragma unroll
    for (int i = 0; i < 4; ++i)
#pragma unroll
        for (int j = 0; j < 4; ++j) acc[i][j] = (f32x4){0.f, 0.f, 0.f, 0.f};

    for (int k0 = 0; k0 < K; k0 += 32) {
        {
            float va[16];
            int g = row0 + sr;
            if (g < M) {
                const float4* ap = reinterpret_cast<const float4*>(&A[(size_t)g * K + k0 + sc]);
#pragma unroll
                for (int i = 0; i < 4; ++i) *reinterpret_cast<float4*>(&va[i * 4]) = ap[i];
            } else {
#pragma unroll
                for (int i = 0; i < 16; ++i) va[i] = 0.f;
            }
            short hs[16], ls[16];
#pragma unroll
            for (int i = 0; i < 16; ++i) split2(va[i], hs[i], ls[i]);
            *reinterpret_cast<bf16x8*>(&As_h[sr * 32 + sc])     = *reinterpret_cast<bf16x8*>(&hs[0]);
            *reinterpret_cast<bf16x8*>(&As_h[sr * 32 + sc + 8]) = *reinterpret_cast<bf16x8*>(&hs[8]);
            *reinterpret_cast<bf16x8*>(&As_l[sr * 32 + sc])     = *reinterpret_cast<bf16x8*>(&ls[0]);
            *reinterpret_cast<bf16x8*>(&As_l[sr * 32 + sc + 8]) = *reinterpret_cast<bf16x8*>(&ls[8]);
        }
        {
            const short* bhp = &Bh[(size_t)(col0 + sr) * K + k0 + sc];
            const short* blp = &Bl[(size_t)(col0 + sr) * K + k0 + sc];
            *reinterpret_cast<bf16x8*>(&Bs_h[sr * 32 + sc])     = *reinterpret_cast<const bf16x8*>(bhp);
            *reinterpret_cast<bf16x8*>(&Bs_h[sr * 32 + sc + 8]) = *reinterpret_cast<const bf16x8*>(bhp + 8);
            *reinterpret_cast<bf16x8*>(&Bs_l[sr * 32 + sc])     = *reinterpret_cast<const bf16x8*>(blp);
            *reinterpret_cast<bf16x8*>(&Bs_l[sr * 32 + sc + 8]) = *reinterpret_cast<const bf16x8*>(blp + 8);
        }
        __syncthreads();

        bf16x8 ah[4], av[4], bh[4], bv[4];
#pragma unroll
        for (int t = 0; t < 4; ++t) {
            int arow = (wm * 64 + t * 16 + lr) * 32 + lg * 8;
            int brow = (wn * 64 + t * 16 + lr) * 32 + lg * 8;
            ah[t] = *reinterpret_cast<const bf16x8*>(&As_h[arow]);
            av[t] = *reinterpret_cast<const bf16x8*>(&As_l[arow]);
            bh[t] = *reinterpret_cast<const bf16x8*>(&Bs_h[brow]);
            bv[t] = *reinterpret_cast<const bf16x8*>(&Bs_l[brow]);
        }
#pragma unroll
        for (int mt = 0; mt < 4; ++mt)
#pragma unroll
            for (int nt = 0; nt < 4; ++nt) {
                acc[mt][nt] = __builtin_amdgcn_mfma_f32_16x16x32_bf16(ah[mt], bh[nt], acc[mt][nt], 0, 0, 0);
                acc[mt][nt] = __builtin_amdgcn_mfma_f32_16x16x32_bf16(ah[mt], bv[nt], acc[mt][nt], 0, 0, 0);
                acc[mt][nt] = __builtin_amdgcn_mfma_f32_16x16x32_bf16(av[mt], bh[nt], acc[mt][nt], 0, 0, 0);
            }
        __syncthreads();
    }

    const int head = blockIdx.y * 2 + wn;
    float alv[4], arv[4];
    if (ELER) {
#pragma unroll
        for (int nt = 0; nt < 4; ++nt) {
            alv[nt] = al[head * 64 + nt * 16 + lr];
            arv[nt] = ar[head * 64 + nt * 16 + lr];
        }
    }
#pragma unroll
    for (int mt = 0; mt < 4; ++mt) {
#pragma unroll
        for (int r = 0; r < 4; ++r) {
            int row = row0 + wm * 64 + mt * 16 + lg * 4 + r;
            bool valid = row < M;
            float sl = 0.f, sr_ = 0.f;
#pragma unroll
            for (int nt = 0; nt < 4; ++nt) {
                float v = acc[mt][nt][r];
                if (TANH) v = fast_tanh(v);
                if (valid) C[(size_t)row * 256 + col0 + wn * 64 + nt * 16 + lr] = v;
                if (ELER) { sl = fmaf(v, alv[nt], sl); sr_ = fmaf(v, arv[nt], sr_); }
            }
            if (ELER) {
#pragma unroll
                for (int mask = 1; mask < 16; mask <<= 1) {
                    sl  += __shfl_xor(sl, mask, 16);
                    sr_ += __shfl_xor(sr_, mask, 16);
                }
                if (valid && lr == 0) {
                    el[row * 4 + head] = sl;
                    er[row * 4 + head] = sr_;
                }
            }
        }
    }
}

// ---------------- CSR build ------------------------------------------------
__global__ void count_deg_kernel(const int* __restrict__ dst, int* __restrict__ deg, int E) {
    int i = blockIdx.x * blockDim.x + threadIdx.x;
    if (i < E) atomicAdd(&deg[dst[i]], 1);
}

__global__ __launch_bounds__(1024) void scan_kernel(const int* __restrict__ deg,
                                                    int* __restrict__ offs,
                                                    int* __restrict__ cursor, int n) {
    __shared__ int wsum[16];
    const int tid = threadIdx.x, lane = tid & 63, wv = tid >> 6;
    int carry = 0;
    for (int base = 0; base < n; base += 1024) {
        int i = base + tid;
        int v = (i < n) ? deg[i] : 0;
        int incl = v;
#pragma unroll
        for (int d = 1; d < 64; d <<= 1) {
            int t = __shfl_up(incl, d, 64);
            if (lane >= d) incl += t;
        }
        if (lane == 63) wsum[wv] = incl;
        __syncthreads();
        int woff = 0, tot = 0;
#pragma unroll
        for (int w2 = 0; w2 < 16; ++w2) {
            int s = wsum[w2];
            if (w2 < wv) woff += s;
            tot += s;
        }
        int excl = carry + woff + incl - v;
        if (i < n) { offs[i] = excl; cursor[i] = excl; }
        carry += tot;
        __syncthreads();
    }
    if (tid == 0) offs[n] = carry;
}

__global__ void fill_csr_kernel(const int* __restrict__ src, const int* __restrict__ dst,
                                int* __restrict__ cursor, int* __restrict__ srcs_sorted,
                                int* __restrict__ dsts_sorted, int E) {
    int i = blockIdx.x * blockDim.x + threadIdx.x;
    if (i < E) {
        int d = dst[i];
        int pos = atomicAdd(&cursor[d], 1);
        srcs_sorted[pos] = src[i];
        dsts_sorted[pos] = d;
    }
}

// ---------------- edge weights: w[pos] = exp(leaky(el[src] + er[dst])) -----
// el table (800 KB) is L2-resident; er reads are dst-sorted (quasi-seq);
// w written sequentially in CSR order.
__global__ __launch_bounds__(256) void edge_w_kernel(const int* __restrict__ srcs,
                                                     const int* __restrict__ dsts,
                                                     const float* __restrict__ el,
                                                     const float* __restrict__ er,
                                                     float4* __restrict__ w, int E) {
    int i = blockIdx.x * 256 + threadIdx.x;
    if (i >= E) return;
    int s = srcs[i], d = dsts[i];
    const float4 a = *reinterpret_cast<const float4*>(&el[(size_t)s * 4]);
    const float4 b = *reinterpret_cast<const float4*>(&er[(size_t)d * 4]);
    float4 o;
    o.x = __expf(leaky02(a.x + b.x));
    o.y = __expf(leaky02(a.y + b.y));
    o.z = __expf(leaky02(a.z + b.z));
    o.w = __expf(leaky02(a.w + b.w));
    w[i] = o;
}

// ---------------- GAT aggregation: wave/node, precomputed weights ----------
// Inner loop: sequential scalar idx + w loads, 8 independent feat gathers.
template<bool FINAL>
__global__ __launch_bounds__(256) void gat_agg_kernel(const float* __restrict__ feat,
                                                      const float4* __restrict__ wq,
                                                      const int* __restrict__ srcs,
                                                      const int* __restrict__ offs,
                                                      const float* __restrict__ bias,
                                                      float* __restrict__ out, int N) {
    const int tid = threadIdx.x;
    const int w = tid >> 6, l = tid & 63;
    const int n = blockIdx.x * 4 + w;
    if (n >= N) return;
    const int h = l >> 4;                // head of this lane's 4 channels
    const int begin = offs[n];
    const int deg = offs[n + 1] - begin;
    const float* fbase = feat + (size_t)l * 4;
    const float4 zero4 = make_float4(0.f, 0.f, 0.f, 0.f);

    float4 acc = zero4;
    float z = 0.f;

    for (int j = 0; j < deg; j += 8) {
        const int rem = deg - j;  // wave-uniform
        const int nb = __builtin_amdgcn_readfirstlane(begin + j);
        // sequential scalar index loads
        const int s0 = srcs[nb + 0];
        const int s1 = (rem > 1) ? srcs[nb + 1] : 0;
        const int s2 = (rem > 2) ? srcs[nb + 2] : 0;
        const int s3 = (rem > 3) ? srcs[nb + 3] : 0;
        const int s4 = (rem > 4) ? srcs[nb + 4] : 0;
        const int s5 = (rem > 5) ? srcs[nb + 5] : 0;
        const int s6 = (rem > 6) ? srcs[nb + 6] : 0;
        const int s7 = (rem > 7) ? srcs[nb + 7] : 0;
        // sequential scalar weight loads (tail -> 0 weights)
        const float4 w0 = wq[nb + 0];
        const float4 w1 = (rem > 1) ? wq[nb + 1] : zero4;
        const float4 w2 = (rem > 2) ? wq[nb + 2] : zero4;
        const float4 w3 = (rem > 3) ? wq[nb + 3] : zero4;
        const float4 w4 = (rem > 4) ? wq[nb + 4] : zero4;
        const float4 w5 = (rem > 5) ? wq[nb + 5] : zero4;
        const float4 w6 = (rem > 6) ? wq[nb + 6] : zero4;
        const float4 w7 = (rem > 7) ? wq[nb + 7] : zero4;
        // 8 independent feat-row loads (the only random VMEM stream)
        const float4 f0 = *reinterpret_cast<const float4*>(fbase + (size_t)s0 * 256);
        const float4 f1 = *reinterpret_cast<const float4*>(fbase + (size_t)s1 * 256);
        const float4 f2 = *reinterpret_cast<const float4*>(fbase + (size_t)s2 * 256);
        const float4 f3 = *reinterpret_cast<const float4*>(fbase + (size_t)s3 * 256);
        const float4 f4 = *reinterpret_cast<const float4*>(fbase + (size_t)s4 * 256);
        const float4 f5 = *reinterpret_cast<const float4*>(fbase + (size_t)s5 * 256);
        const float4 f6 = *reinterpret_cast<const float4*>(fbase + (size_t)s6 * 256);
        const float4 f7 = *reinterpret_cast<const float4*>(fbase + (size_t)s7 * 256);

        const float e0 = sel_head(w0, h);
        const float e1 = sel_head(w1, h);
        const float e2 = sel_head(w2, h);
        const float e3 = sel_head(w3, h);
        const float e4 = sel_head(w4, h);
        const float e5 = sel_head(w5, h);
        const float e6 = sel_head(w6, h);
        const float e7 = sel_head(w7, h);
        z += ((e0 + e1) + (e2 + e3)) + ((e4 + e5) + (e6 + e7));
        acc.x = fmaf(e0, f0.x, acc.x); acc.y = fmaf(e0, f0.y, acc.y);
        acc.z = fmaf(e0, f0.z, acc.z); acc.w = fmaf(e0, f0.w, acc.w);
        acc.x = fmaf(e1, f1.x, acc.x); acc.y = fmaf(e1, f1.y, acc.y);
        acc.z = fmaf(e1, f1.z, acc.z); acc.w = fmaf(e1, f1.w, acc.w);
        acc.x = fmaf(e2, f2.x, acc.x); acc.y = fmaf(e2, f2.y, acc.y);
        acc.z = fmaf(e2, f2.z, acc.z); acc.w = fmaf(e2, f2.w, acc.w);
        acc.x = fmaf(e3, f3.x, acc.x); acc.y = fmaf(e3, f3.y, acc.y);
        acc.z = fmaf(e3, f3.z, acc.z); acc.w = fmaf(e3, f3.w, acc.w);
        acc.x = fmaf(e4, f4.x, acc.x); acc.y = fmaf(e4, f4.y, acc.y);
        acc.z = fmaf(e4, f4.z, acc.z); acc.w = fmaf(e4, f4.w, acc.w);
        acc.x = fmaf(e5, f5.x, acc.x); acc.y = fmaf(e5, f5.y, acc.y);
        acc.z = fmaf(e5, f5.z, acc.z); acc.w = fmaf(e5, f5.w, acc.w);
        acc.x = fmaf(e6, f6.x, acc.x); acc.y = fmaf(e6, f6.y, acc.y);
        acc.z = fmaf(e6, f6.z, acc.z); acc.w = fmaf(e6, f6.w, acc.w);
        acc.x = fmaf(e7, f7.x, acc.x); acc.y = fmaf(e7, f7.y, acc.y);
        acc.z = fmaf(e7, f7.z, acc.z); acc.w = fmaf(e7, f7.w, acc.w);
    }

    const float rz = (z > 0.f) ? __builtin_amdgcn_rcpf(z) : 0.f;
    const float4 bv = *reinterpret_cast<const float4*>(&bias[l * 4]);
    float4 v;
    v.x = fmaf(acc.x, rz, bv.x);
    v.y = fmaf(acc.y, rz, bv.y);
    v.z = fmaf(acc.z, rz, bv.z);
    v.w = fmaf(acc.w, rz, bv.w);
    v.x = v.x > 0.f ? v.x : expm1f(v.x);
    v.y = v.y > 0.f ? v.y : expm1f(v.y);
    v.z = v.z > 0.f ? v.z : expm1f(v.z);
    v.w = v.w > 0.f ? v.w : expm1f(v.w);

    if (!FINAL) {
        *reinterpret_cast<float4*>(&out[(size_t)n * 256 + l * 4]) = v;
    } else {
        v.x += __shfl_down(v.x, 32, 64); v.y += __shfl_down(v.y, 32, 64);
        v.z += __shfl_down(v.z, 32, 64); v.w += __shfl_down(v.w, 32, 64);
        v.x += __shfl_down(v.x, 16, 64); v.y += __shfl_down(v.y, 16, 64);
        v.z += __shfl_down(v.z, 16, 64); v.w += __shfl_down(v.w, 16, 64);
        if (l < 16) {
            float4 o;
            o.x = 0.25f * v.x; o.y = 0.25f * v.y; o.z = 0.25f * v.z; o.w = 0.25f * v.w;
            *reinterpret_cast<float4*>(&out[(size_t)n * 64 + l * 4]) = o;
        }
    }
}

// ---------------------------------------------------------------------------
extern "C" void kernel_launch(void* const* d_in, const int* in_sizes, int n_in,
                              void* d_out, int out_size, void* d_ws, size_t ws_size,
                              hipStream_t stream) {
    const float* x_feat = (const float*)d_in[0];
    const float* W_fc   = (const float*)d_in[1];
    const float* W1     = (const float*)d_in[2];
    const float* al1    = (const float*)d_in[3];
    const float* ar1    = (const float*)d_in[4];
    const float* b1     = (const float*)d_in[5];
    const float* W2     = (const float*)d_in[6];
    const float* al2    = (const float*)d_in[7];
    const float* ar2    = (const float*)d_in[8];
    const float* b2     = (const float*)d_in[9];
    const int*   src    = (const int*)d_in[10];
    const int*   dst    = (const int*)d_in[11];
    float* out = (float*)d_out;

    const int N = in_sizes[0] / 128;   // 50000
    const int E = in_sizes[10];        // 800000

    char* ws = (char*)d_ws;
    size_t off = 0;
    auto alloc = [&](size_t bytes) -> void* {
        off = (off + 255) & ~(size_t)255;
        void* p = ws + off;
        off += bytes;
        return p;
    };
    float* buf0 = (float*)alloc((size_t)N * 256 * 4);  // h, later g1
    float* buf1 = (float*)alloc((size_t)N * 256 * 4);  // feat1, later feat2
    float* el   = (float*)alloc((size_t)N * 4 * 4);
    float* er   = (float*)alloc((size_t)N * 4 * 4);
    int* deg    = (int*)alloc((size_t)N * 4);
    int* offs   = (int*)alloc((size_t)(N + 1) * 4);
    int* cursor = (int*)alloc((size_t)N * 4);
    int* srcs_sorted = (int*)alloc((size_t)(E + 8) * 4);
    int* dsts_sorted = (int*)alloc((size_t)(E + 8) * 4);
    float4* wq  = (float4*)alloc((size_t)(E + 8) * 16);
    short* Bfc_h = (short*)alloc((size_t)256 * 128 * 2);
    short* Bfc_l = (short*)alloc((size_t)256 * 128 * 2);
    short* B1_h  = (short*)alloc((size_t)256 * 256 * 2);
    short* B1_l  = (short*)alloc((size_t)256 * 256 * 2);
    short* B2_h  = (short*)alloc((size_t)256 * 256 * 2);
    short* B2_l  = (short*)alloc((size_t)256 * 256 * 2);

    const int eb = (E + 255) / 256;
    dim3 ggrid((N + 127) / 128, 2);
    const int agrid = (N + 3) / 4;

    // CSR build (by dst)
    hipMemsetAsync(deg, 0, (size_t)N * 4, stream);
    count_deg_kernel<<<eb, 256, 0, stream>>>(dst, deg, E);
    scan_kernel<<<1, 1024, 0, stream>>>(deg, offs, cursor, N);
    fill_csr_kernel<<<eb, 256, 0, stream>>>(src, dst, cursor, srcs_sorted, dsts_sorted, E);

    // weight splits (single launch)
    wsplit3_kernel<<<(128 * 256 + 2 * 256 * 256 + 255) / 256, 256, 0, stream>>>(
        W_fc, Bfc_h, Bfc_l, W1, B1_h, B1_l, W2, B2_h, B2_l);

    // h = tanh(x @ W_fc)
    mfma_gemm_kernel<true, false><<<ggrid, 256, 0, stream>>>(
        x_feat, Bfc_h, Bfc_l, buf0, N, 128, nullptr, nullptr, nullptr, nullptr);
    // feat1 = h @ W1 (+ el/er)
    mfma_gemm_kernel<false, true><<<ggrid, 256, 0, stream>>>(
        buf0, B1_h, B1_l, buf1, N, 256, al1, ar1, el, er);
    // edge weights for layer 1
    edge_w_kernel<<<eb, 256, 0, stream>>>(srcs_sorted, dsts_sorted, el, er, wq, E);
    // g1 -> buf0
    gat_agg_kernel<false><<<agrid, 256, 0, stream>>>(buf1, wq, srcs_sorted, offs, b1, buf0, N);
    // feat2 = g1 @ W2 (+ el/er)
    mfma_gemm_kernel<false, true><<<ggrid, 256, 0, stream>>>(
        buf0, B2_h, B2_l, buf1, N, 256, al2, ar2, el, er);
    // edge weights for layer 2
    edge_w_kernel<<<eb, 256, 0, stream>>>(srcs_sorted, dsts_sorted, el, er, wq, E);
    // final aggregation + head mean -> out
    gat_agg_kernel<true><<<agrid, 256, 0, stream>>>(buf1, wq, srcs_sorted, offs, b2, out, N);
}

// Round 8
// 463.327 us; speedup vs baseline: 1.2109x; 1.2109x over previous
//
#include <hip/hip_runtime.h>
#include <hip/hip_bf16.h>
#include <hip/hip_fp16.h>
#include <math.h>

// ---------------------------------------------------------------------------
// HomoGAT on MI355X.
//  - GEMMs: split-precision bf16 MFMA (A=Ah+Al, B=Bh+Bl, 3 products, fp32 acc).
//  - feat1/feat2 (gather tables) stored as FP16: halves random-gather traffic,
//    which sits at the chip's ~3.7 TB/s random-line ceiling (R5-R7 evidence).
//  - Aggregation: CSR by dst, wave-per-node, precomputed edge weights,
//    8 fp16 feat rows in flight.
// ---------------------------------------------------------------------------

typedef __attribute__((ext_vector_type(8))) short bf16x8;
typedef __attribute__((ext_vector_type(4))) float f32x4;

__device__ __forceinline__ void split2(float v, short& h, short& l) {
    __hip_bfloat16 bh = __float2bfloat16(v);
    float r = v - __bfloat162float(bh);
    __hip_bfloat16 bl = __float2bfloat16(r);
    h = *reinterpret_cast<short*>(&bh);
    l = *reinterpret_cast<short*>(&bl);
}

__device__ __forceinline__ float fast_tanh(float x) {
    x = fminf(fmaxf(x, -15.f), 15.f);
    float e = __expf(2.f * x);
    return (e - 1.f) * __builtin_amdgcn_rcpf(e + 1.f);
}

__device__ __forceinline__ float leaky02(float x) { return x > 0.f ? x : 0.2f * x; }

__device__ __forceinline__ float sel_head(float4 q, int h) {
    float lo = (h & 1) ? q.y : q.x;
    float hi = (h & 1) ? q.w : q.z;
    return (h & 2) ? hi : lo;
}

// ---------------- weight split (all 3 weight matrices in one launch) -------
__global__ __launch_bounds__(256) void wsplit3_kernel(
        const float* __restrict__ W0, short* __restrict__ B0h, short* __restrict__ B0l,
        const float* __restrict__ W1, short* __restrict__ B1h, short* __restrict__ B1l,
        const float* __restrict__ W2, short* __restrict__ B2h, short* __restrict__ B2l) {
    int idx = blockIdx.x * 256 + threadIdx.x;
    const float* W;
    short *Bh, *Bl;
    int K, rel;
    if (idx < 128 * 256) {
        W = W0; Bh = B0h; Bl = B0l; K = 128; rel = idx;
    } else if (idx < 128 * 256 + 256 * 256) {
        W = W1; Bh = B1h; Bl = B1l; K = 256; rel = idx - 128 * 256;
    } else if (idx < 128 * 256 + 2 * 256 * 256) {
        W = W2; Bh = B2h; Bl = B2l; K = 256; rel = idx - 128 * 256 - 256 * 256;
    } else {
        return;
    }
    int k = rel >> 8, n = rel & 255;
    short h, l;
    split2(W[rel], h, l);
    Bh[n * K + k] = h;
    Bl[n * K + k] = l;
}

// ---------------- MFMA GEMM: C[M,256] = A[M,K] @ B[K,256] ------------------
// HALF_OUT: write C as fp16 (gather table); else fp32.
// TANH: apply tanh. ELER: fused el/er head-dots (wave spans one head).
template<bool TANH, bool ELER, bool HALF_OUT>
__global__ __launch_bounds__(256, 2) void mfma_gemm_kernel(
        const float* __restrict__ A, const short* __restrict__ Bh,
        const short* __restrict__ Bl, float* __restrict__ C,
        __half* __restrict__ C16, int M, int K,
        const float* __restrict__ al, const float* __restrict__ ar,
        float* __restrict__ el, float* __restrict__ er) {
    __shared__ __align__(16) short As_h[128 * 32];
    __shared__ __align__(16) short As_l[128 * 32];
    __shared__ __align__(16) short Bs_h[128 * 32];
    __shared__ __align__(16) short Bs_l[128 * 32];

    const int tid = threadIdx.x;
    const int row0 = blockIdx.x * 128;
    const int col0 = blockIdx.y * 128;

    const int sr = tid >> 1;          // 0..127
    const int sc = (tid & 1) << 4;    // 0 or 16

    const int lane = tid & 63;
    const int lr = lane & 15;
    const int lg = lane >> 4;
    const int wid = tid >> 6;
    const int wm = wid >> 1;
    const int wn = wid & 1;

    f32x4 acc[4][4];
#pragma unroll
    for (int i = 0; i < 4; ++i)
#pragma unroll
        for (int j = 0; j < 4; ++j) acc[i][j] = (f32x4){0.f, 0.f, 0.f, 0.f};

    for (int k0 = 0; k0 < K; k0 += 32) {
        {
            float va[16];
            int g = row0 + sr;
            if (g < M) {
                const float4* ap = reinterpret_cast<const float4*>(&A[(size_t)g * K + k0 + sc]);
#pragma unroll
                for (int i = 0; i < 4; ++i) *reinterpret_cast<float4*>(&va[i * 4]) = ap[i];
            } else {
#pragma unroll
                for (int i = 0; i < 16; ++i) va[i] = 0.f;
            }
            short hs[16], ls[16];
#pragma unroll
            for (int i = 0; i < 16; ++i) split2(va[i], hs[i], ls[i]);
            *reinterpret_cast<bf16x8*>(&As_h[sr * 32 + sc])     = *reinterpret_cast<bf16x8*>(&hs[0]);
            *reinterpret_cast<bf16x8*>(&As_h[sr * 32 + sc + 8]) = *reinterpret_cast<bf16x8*>(&hs[8]);
            *reinterpret_cast<bf16x8*>(&As_l[sr * 32 + sc])     = *reinterpret_cast<bf16x8*>(&ls[0]);
            *reinterpret_cast<bf16x8*>(&As_l[sr * 32 + sc + 8]) = *reinterpret_cast<bf16x8*>(&ls[8]);
        }
        {
            const short* bhp = &Bh[(size_t)(col0 + sr) * K + k0 + sc];
            const short* blp = &Bl[(size_t)(col0 + sr) * K + k0 + sc];
            *reinterpret_cast<bf16x8*>(&Bs_h[sr * 32 + sc])     = *reinterpret_cast<const bf16x8*>(bhp);
            *reinterpret_cast<bf16x8*>(&Bs_h[sr * 32 + sc + 8]) = *reinterpret_cast<const bf16x8*>(bhp + 8);
            *reinterpret_cast<bf16x8*>(&Bs_l[sr * 32 + sc])     = *reinterpret_cast<const bf16x8*>(blp);
            *reinterpret_cast<bf16x8*>(&Bs_l[sr * 32 + sc + 8]) = *reinterpret_cast<const bf16x8*>(blp + 8);
        }
        __syncthreads();

        bf16x8 ah[4], av[4], bh[4], bv[4];
#pragma unroll
        for (int t = 0; t < 4; ++t) {
            int arow = (wm * 64 + t * 16 + lr) * 32 + lg * 8;
            int brow = (wn * 64 + t * 16 + lr) * 32 + lg * 8;
            ah[t] = *reinterpret_cast<const bf16x8*>(&As_h[arow]);
            av[t] = *reinterpret_cast<const bf16x8*>(&As_l[arow]);
            bh[t] = *reinterpret_cast<const bf16x8*>(&Bs_h[brow]);
            bv[t] = *reinterpret_cast<const bf16x8*>(&Bs_l[brow]);
        }
#pragma unroll
        for (int mt = 0; mt < 4; ++mt)
#pragma unroll
            for (int nt = 0; nt < 4; ++nt) {
                acc[mt][nt] = __builtin_amdgcn_mfma_f32_16x16x32_bf16(ah[mt], bh[nt], acc[mt][nt], 0, 0, 0);
                acc[mt][nt] = __builtin_amdgcn_mfma_f32_16x16x32_bf16(ah[mt], bv[nt], acc[mt][nt], 0, 0, 0);
                acc[mt][nt] = __builtin_amdgcn_mfma_f32_16x16x32_bf16(av[mt], bh[nt], acc[mt][nt], 0, 0, 0);
            }
        __syncthreads();
    }

    const int head = blockIdx.y * 2 + wn;
    float alv[4], arv[4];
    if (ELER) {
#pragma unroll
        for (int nt = 0; nt < 4; ++nt) {
            alv[nt] = al[head * 64 + nt * 16 + lr];
            arv[nt] = ar[head * 64 + nt * 16 + lr];
        }
    }
#pragma unroll
    for (int mt = 0; mt < 4; ++mt) {
#pragma unroll
        for (int r = 0; r < 4; ++r) {
            int row = row0 + wm * 64 + mt * 16 + lg * 4 + r;
            bool valid = row < M;
            float sl = 0.f, sr_ = 0.f;
#pragma unroll
            for (int nt = 0; nt < 4; ++nt) {
                float v = acc[mt][nt][r];
                if (TANH) v = fast_tanh(v);
                if (valid) {
                    size_t ci = (size_t)row * 256 + col0 + wn * 64 + nt * 16 + lr;
                    if (HALF_OUT) C16[ci] = __float2half(v);
                    else          C[ci] = v;
                }
                if (ELER) { sl = fmaf(v, alv[nt], sl); sr_ = fmaf(v, arv[nt], sr_); }
            }
            if (ELER) {
#pragma unroll
                for (int mask = 1; mask < 16; mask <<= 1) {
                    sl  += __shfl_xor(sl, mask, 16);
                    sr_ += __shfl_xor(sr_, mask, 16);
                }
                if (valid && lr == 0) {
                    el[row * 4 + head] = sl;
                    er[row * 4 + head] = sr_;
                }
            }
        }
    }
}

// ---------------- CSR build ------------------------------------------------
__global__ void count_deg_kernel(const int* __restrict__ dst, int* __restrict__ deg, int E) {
    int i = blockIdx.x * blockDim.x + threadIdx.x;
    if (i < E) atomicAdd(&deg[dst[i]], 1);
}

__global__ __launch_bounds__(1024) void scan_kernel(const int* __restrict__ deg,
                                                    int* __restrict__ offs,
                                                    int* __restrict__ cursor, int n) {
    __shared__ int wsum[16];
    const int tid = threadIdx.x, lane = tid & 63, wv = tid >> 6;
    int carry = 0;
    for (int base = 0; base < n; base += 1024) {
        int i = base + tid;
        int v = (i < n) ? deg[i] : 0;
        int incl = v;
#pragma unroll
        for (int d = 1; d < 64; d <<= 1) {
            int t = __shfl_up(incl, d, 64);
            if (lane >= d) incl += t;
        }
        if (lane == 63) wsum[wv] = incl;
        __syncthreads();
        int woff = 0, tot = 0;
#pragma unroll
        for (int w2 = 0; w2 < 16; ++w2) {
            int s = wsum[w2];
            if (w2 < wv) woff += s;
            tot += s;
        }
        int excl = carry + woff + incl - v;
        if (i < n) { offs[i] = excl; cursor[i] = excl; }
        carry += tot;
        __syncthreads();
    }
    if (tid == 0) offs[n] = carry;
}

__global__ void fill_csr_kernel(const int* __restrict__ src, const int* __restrict__ dst,
                                int* __restrict__ cursor, int* __restrict__ srcs_sorted,
                                int* __restrict__ dsts_sorted, int E) {
    int i = blockIdx.x * blockDim.x + threadIdx.x;
    if (i < E) {
        int d = dst[i];
        int pos = atomicAdd(&cursor[d], 1);
        srcs_sorted[pos] = src[i];
        dsts_sorted[pos] = d;
    }
}

// ---------------- edge weights: w[pos] = exp(leaky(el[src] + er[dst])) -----
__global__ __launch_bounds__(256) void edge_w_kernel(const int* __restrict__ srcs,
                                                     const int* __restrict__ dsts,
                                                     const float* __restrict__ el,
                                                     const float* __restrict__ er,
                                                     float4* __restrict__ w, int E) {
    int i = blockIdx.x * 256 + threadIdx.x;
    if (i >= E) return;
    int s = srcs[i], d = dsts[i];
    const float4 a = *reinterpret_cast<const float4*>(&el[(size_t)s * 4]);
    const float4 b = *reinterpret_cast<const float4*>(&er[(size_t)d * 4]);
    float4 o;
    o.x = __expf(leaky02(a.x + b.x));
    o.y = __expf(leaky02(a.y + b.y));
    o.z = __expf(leaky02(a.z + b.z));
    o.w = __expf(leaky02(a.w + b.w));
    w[i] = o;
}

// ---------------- GAT aggregation: wave/node, fp16 rows, precomputed w -----
template<bool FINAL>
__global__ __launch_bounds__(256) void gat_agg_kernel(const __half* __restrict__ feat,
                                                      const float4* __restrict__ wq,
                                                      const int* __restrict__ srcs,
                                                      const int* __restrict__ offs,
                                                      const float* __restrict__ bias,
                                                      float* __restrict__ out, int N) {
    const int tid = threadIdx.x;
    const int w = tid >> 6, l = tid & 63;
    const int n = blockIdx.x * 4 + w;
    if (n >= N) return;
    const int h = l >> 4;                // head of this lane's 4 channels
    const int begin = offs[n];
    const int deg = offs[n + 1] - begin;
    const __half* fbase = feat + (size_t)l * 4;
    const float4 zero4 = make_float4(0.f, 0.f, 0.f, 0.f);

    float4 acc = zero4;
    float z = 0.f;

    for (int j = 0; j < deg; j += 8) {
        const int rem = deg - j;  // wave-uniform
        const int nb = __builtin_amdgcn_readfirstlane(begin + j);
        // sequential scalar index loads (tail -> node 0, weight 0)
        const int s0 = srcs[nb + 0];
        const int s1 = (rem > 1) ? srcs[nb + 1] : 0;
        const int s2 = (rem > 2) ? srcs[nb + 2] : 0;
        const int s3 = (rem > 3) ? srcs[nb + 3] : 0;
        const int s4 = (rem > 4) ? srcs[nb + 4] : 0;
        const int s5 = (rem > 5) ? srcs[nb + 5] : 0;
        const int s6 = (rem > 6) ? srcs[nb + 6] : 0;
        const int s7 = (rem > 7) ? srcs[nb + 7] : 0;
        // sequential weight loads
        const float4 w0 = wq[nb + 0];
        const float4 w1 = (rem > 1) ? wq[nb + 1] : zero4;
        const float4 w2 = (rem > 2) ? wq[nb + 2] : zero4;
        const float4 w3 = (rem > 3) ? wq[nb + 3] : zero4;
        const float4 w4 = (rem > 4) ? wq[nb + 4] : zero4;
        const float4 w5 = (rem > 5) ? wq[nb + 5] : zero4;
        const float4 w6 = (rem > 6) ? wq[nb + 6] : zero4;
        const float4 w7 = (rem > 7) ? wq[nb + 7] : zero4;
        // 8 independent fp16 feat-row loads (8B/lane, the only random stream)
        const uint2 u0 = *reinterpret_cast<const uint2*>(fbase + (size_t)s0 * 256);
        const uint2 u1 = *reinterpret_cast<const uint2*>(fbase + (size_t)s1 * 256);
        const uint2 u2 = *reinterpret_cast<const uint2*>(fbase + (size_t)s2 * 256);
        const uint2 u3 = *reinterpret_cast<const uint2*>(fbase + (size_t)s3 * 256);
        const uint2 u4 = *reinterpret_cast<const uint2*>(fbase + (size_t)s4 * 256);
        const uint2 u5 = *reinterpret_cast<const uint2*>(fbase + (size_t)s5 * 256);
        const uint2 u6 = *reinterpret_cast<const uint2*>(fbase + (size_t)s6 * 256);
        const uint2 u7 = *reinterpret_cast<const uint2*>(fbase + (size_t)s7 * 256);

        const float e0 = sel_head(w0, h);
        const float e1 = sel_head(w1, h);
        const float e2 = sel_head(w2, h);
        const float e3 = sel_head(w3, h);
        const float e4 = sel_head(w4, h);
        const float e5 = sel_head(w5, h);
        const float e6 = sel_head(w6, h);
        const float e7 = sel_head(w7, h);
        z += ((e0 + e1) + (e2 + e3)) + ((e4 + e5) + (e6 + e7));

        auto fma4 = [&](float e, uint2 u) {
            const __half2* hp = reinterpret_cast<const __half2*>(&u);
            float2 a = __half22float2(hp[0]);
            float2 b = __half22float2(hp[1]);
            acc.x = fmaf(e, a.x, acc.x); acc.y = fmaf(e, a.y, acc.y);
            acc.z = fmaf(e, b.x, acc.z); acc.w = fmaf(e, b.y, acc.w);
        };
        fma4(e0, u0); fma4(e1, u1); fma4(e2, u2); fma4(e3, u3);
        fma4(e4, u4); fma4(e5, u5); fma4(e6, u6); fma4(e7, u7);
    }

    const float rz = (z > 0.f) ? __builtin_amdgcn_rcpf(z) : 0.f;
    const float4 bv = *reinterpret_cast<const float4*>(&bias[l * 4]);
    float4 v;
    v.x = fmaf(acc.x, rz, bv.x);
    v.y = fmaf(acc.y, rz, bv.y);
    v.z = fmaf(acc.z, rz, bv.z);
    v.w = fmaf(acc.w, rz, bv.w);
    v.x = v.x > 0.f ? v.x : expm1f(v.x);
    v.y = v.y > 0.f ? v.y : expm1f(v.y);
    v.z = v.z > 0.f ? v.z : expm1f(v.z);
    v.w = v.w > 0.f ? v.w : expm1f(v.w);

    if (!FINAL) {
        *reinterpret_cast<float4*>(&out[(size_t)n * 256 + l * 4]) = v;
    } else {
        v.x += __shfl_down(v.x, 32, 64); v.y += __shfl_down(v.y, 32, 64);
        v.z += __shfl_down(v.z, 32, 64); v.w += __shfl_down(v.w, 32, 64);
        v.x += __shfl_down(v.x, 16, 64); v.y += __shfl_down(v.y, 16, 64);
        v.z += __shfl_down(v.z, 16, 64); v.w += __shfl_down(v.w, 16, 64);
        if (l < 16) {
            float4 o;
            o.x = 0.25f * v.x; o.y = 0.25f * v.y; o.z = 0.25f * v.z; o.w = 0.25f * v.w;
            *reinterpret_cast<float4*>(&out[(size_t)n * 64 + l * 4]) = o;
        }
    }
}

// ---------------------------------------------------------------------------
extern "C" void kernel_launch(void* const* d_in, const int* in_sizes, int n_in,
                              void* d_out, int out_size, void* d_ws, size_t ws_size,
                              hipStream_t stream) {
    const float* x_feat = (const float*)d_in[0];
    const float* W_fc   = (const float*)d_in[1];
    const float* W1     = (const float*)d_in[2];
    const float* al1    = (const float*)d_in[3];
    const float* ar1    = (const float*)d_in[4];
    const float* b1     = (const float*)d_in[5];
    const float* W2     = (const float*)d_in[6];
    const float* al2    = (const float*)d_in[7];
    const float* ar2    = (const float*)d_in[8];
    const float* b2     = (const float*)d_in[9];
    const int*   src    = (const int*)d_in[10];
    const int*   dst    = (const int*)d_in[11];
    float* out = (float*)d_out;

    const int N = in_sizes[0] / 128;   // 50000
    const int E = in_sizes[10];        // 800000

    char* ws = (char*)d_ws;
    size_t off = 0;
    auto alloc = [&](size_t bytes) -> void* {
        off = (off + 255) & ~(size_t)255;
        void* p = ws + off;
        off += bytes;
        return p;
    };
    float* buf0  = (float*)alloc((size_t)N * 256 * 4);   // h, later g1 (fp32: GEMM-A)
    __half* f16  = (__half*)alloc((size_t)N * 256 * 2);  // feat1 / feat2 gather table
    float* el    = (float*)alloc((size_t)N * 4 * 4);
    float* er    = (float*)alloc((size_t)N * 4 * 4);
    int* deg     = (int*)alloc((size_t)N * 4);
    int* offs    = (int*)alloc((size_t)(N + 1) * 4);
    int* cursor  = (int*)alloc((size_t)N * 4);
    int* srcs_sorted = (int*)alloc((size_t)(E + 8) * 4);
    int* dsts_sorted = (int*)alloc((size_t)(E + 8) * 4);
    float4* wq   = (float4*)alloc((size_t)(E + 8) * 16);
    short* Bfc_h = (short*)alloc((size_t)256 * 128 * 2);
    short* Bfc_l = (short*)alloc((size_t)256 * 128 * 2);
    short* B1_h  = (short*)alloc((size_t)256 * 256 * 2);
    short* B1_l  = (short*)alloc((size_t)256 * 256 * 2);
    short* B2_h  = (short*)alloc((size_t)256 * 256 * 2);
    short* B2_l  = (short*)alloc((size_t)256 * 256 * 2);

    const int eb = (E + 255) / 256;
    dim3 ggrid((N + 127) / 128, 2);
    const int agrid = (N + 3) / 4;

    // CSR build (by dst)
    hipMemsetAsync(deg, 0, (size_t)N * 4, stream);
    count_deg_kernel<<<eb, 256, 0, stream>>>(dst, deg, E);
    scan_kernel<<<1, 1024, 0, stream>>>(deg, offs, cursor, N);
    fill_csr_kernel<<<eb, 256, 0, stream>>>(src, dst, cursor, srcs_sorted, dsts_sorted, E);

    // weight splits (single launch)
    wsplit3_kernel<<<(128 * 256 + 2 * 256 * 256 + 255) / 256, 256, 0, stream>>>(
        W_fc, Bfc_h, Bfc_l, W1, B1_h, B1_l, W2, B2_h, B2_l);

    // h = tanh(x @ W_fc)  (fp32 out: GEMM-A for layer 1)
    mfma_gemm_kernel<true, false, false><<<ggrid, 256, 0, stream>>>(
        x_feat, Bfc_h, Bfc_l, buf0, nullptr, N, 128, nullptr, nullptr, nullptr, nullptr);
    // feat1 = h @ W1 -> fp16 table (+ el/er fp32)
    mfma_gemm_kernel<false, true, true><<<ggrid, 256, 0, stream>>>(
        buf0, B1_h, B1_l, nullptr, f16, N, 256, al1, ar1, el, er);
    // edge weights for layer 1
    edge_w_kernel<<<eb, 256, 0, stream>>>(srcs_sorted, dsts_sorted, el, er, wq, E);
    // g1 -> buf0 (fp32: GEMM-A for layer 2)
    gat_agg_kernel<false><<<agrid, 256, 0, stream>>>(f16, wq, srcs_sorted, offs, b1, buf0, N);
    // feat2 = g1 @ W2 -> fp16 table (+ el/er)
    mfma_gemm_kernel<false, true, true><<<ggrid, 256, 0, stream>>>(
        buf0, B2_h, B2_l, nullptr, f16, N, 256, al2, ar2, el, er);
    // edge weights for layer 2
    edge_w_kernel<<<eb, 256, 0, stream>>>(srcs_sorted, dsts_sorted, el, er, wq, E);
    // final aggregation + head mean -> out
    gat_agg_kernel<true><<<agrid, 256, 0, stream>>>(f16, wq, srcs_sorted, offs, b2, out, N);
}